// Round 4
// baseline (151.944 us; speedup 1.0000x reference)
//
#include <hip/hip_runtime.h>

#define NS     1500
#define NT     1500
#define NRR    4
#define DD     64
#define NBB    200
#define RJ     30                  // j's held in registers per wave
#define JWAVES 50                  // NT / RJ
#define NU     (NRR * JWAVES)      // 200 (k, j-wave) units
#define CH     75                  // i's per wave-chunk (compile-time!)
#define NCG    5                   // chunk-groups: 5 * 4 waves = 20 chunks = 1500 i
#define NCOMP  (NU * NCG)          // 1000 compute blocks
#define NANCH  8                   // anchor blocks (25 pairs each)
#define NBLK   (NCOMP + NANCH)     // 1008 total ~= 4 blocks/CU, all co-resident
#define EPS    3.0

// ws: [0..3]=loss_all, [4..7]=loss_alm, [8]=counter.  64B memset before launch.
__global__ __launch_bounds__(256) void fused_loss_kernel(
    const float* __restrict__ emb_s,
    const float* __restrict__ emb_t,
    const int*  __restrict__ rows,
    const int*  __restrict__ cols,
    float* __restrict__ ws,
    float* __restrict__ out)
{
    __shared__ float red[4];
    const int tid  = threadIdx.x;
    const int wave = tid >> 6;
    const int lane = tid & 63;          // = d
    const int b    = blockIdx.x;

    if (b < NCOMP) {
        // ---------------- all-pairs path (waves decoupled, no LDS tile) ----
        const int u  = b % NU;          // (k, j-wave) unit, shared by 4 waves
        const int cg = b / NU;          // chunk group
        const int k  = u / JWAVES;
        const int j0 = (u % JWAVES) * RJ;
        const int i0 = (cg * 4 + wave) * CH;   // this wave's 75 i's

        // 30 t-columns in registers: tj[r] = t[j0+r][k][lane]
        const float* tp = emb_t + j0 * (NRR * DD) + k * DD + lane;
        float tj[RJ];
        #pragma unroll
        for (int r = 0; r < RJ; ++r)
            tj[r] = tp[r * (NRR * DD)];

        // stream s rows straight from global (L2-resident), 1-deep prefetch
        const float* sp = emb_s + k * DD + lane;
        float acc[8];
        #pragma unroll
        for (int a = 0; a < 8; ++a) acc[a] = 0.f;

        int i = i0;
        float nxt = sp[i * (NRR * DD)];
        #pragma unroll 5
        for (int ii = 0; ii < CH; ++ii) {
            const float sv = nxt;
            int ipf = i + 1;
            if (ipf > NS - 1) ipf = NS - 1;     // clamp (last chunk only)
            i = ipf;
            nxt = sp[ipf * (NRR * DD)];         // prefetch next i
            #pragma unroll
            for (int r = 0; r < RJ; ++r)
                acc[r & 7] += fabsf(sv - tj[r]);
        }

        float a = ((acc[0] + acc[1]) + (acc[2] + acc[3]))
                + ((acc[4] + acc[5]) + (acc[6] + acc[7]));

        #pragma unroll
        for (int off = 32; off > 0; off >>= 1)
            a += __shfl_down(a, off, 64);
        if (lane == 0) red[wave] = a;           // all 4 waves share the same k
        __syncthreads();
        if (tid == 0)
            atomicAdd(&ws[k], (red[0] + red[1]) + (red[2] + red[3]));
    } else {
        // ---------------- anchor path: 8 blocks x 25 pairs -----------------
        const int ab = b - NCOMP;
        const int k = wave, d = lane;
        float acc = 0.f;
        #pragma unroll 5
        for (int t = 0; t < NBB / NANCH; ++t) {
            const int p = ab + t * NANCH;
            const int r = rows[p];
            const int c = cols[p];
            acc += fabsf(emb_s[(r * NRR + k) * DD + d]
                       - emb_t[(c * NRR + k) * DD + d]);
        }
        #pragma unroll
        for (int off = 32; off > 0; off >>= 1)
            acc += __shfl_down(acc, off, 64);
        if (d == 0) atomicAdd(&ws[4 + k], acc);
    }

    // ---------------- last-block finalize ---------------------------------
    __threadfence();
    if (tid == 0) {
        unsigned old = atomicAdd((unsigned*)&ws[8], 1u);
        if (old == (unsigned)(NBLK - 1)) {
            __threadfence();
            double la[4], lm[4];
            #pragma unroll
            for (int k2 = 0; k2 < 4; ++k2) {
                la[k2] = (double)atomicAdd(&ws[k2], 0.f);       // coherent read
                lm[k2] = (double)atomicAdd(&ws[4 + k2], 0.f);
            }
            const double nbB   = (double)NBB;
            const double nbNot = (double)NS * (double)NT - nbB;
            const double params[4] = {0.4, 0.2, 0.2, 0.2};
            double ret = 0.0;
            for (int k2 = 0; k2 < 4; ++k2) {
                const double notalm = la[k2] - lm[k2];
                const double lk = lm[k2] * nbNot + (EPS * nbNot - notalm) * nbB;
                ret += params[k2] * lk;
            }
            ret = ret / (double)DD / ((double)NS * (double)NT);
            out[0] = (float)ret;
        }
    }
}

extern "C" void kernel_launch(void* const* d_in, const int* in_sizes, int n_in,
                              void* d_out, int out_size, void* d_ws, size_t ws_size,
                              hipStream_t stream)
{
    const float* emb_s = (const float*)d_in[0];
    const float* emb_t = (const float*)d_in[1];
    const int*   rows  = (const int*)d_in[2];
    const int*   cols  = (const int*)d_in[3];
    float* out = (float*)d_out;
    float* ws  = (float*)d_ws;

    hipMemsetAsync(ws, 0, 64, stream);
    fused_loss_kernel<<<NBLK, 256, 0, stream>>>(emb_s, emb_t, rows, cols, ws, out);
}